// Round 3
// baseline (161.863 us; speedup 1.0000x reference)
//
#include <hip/hip_runtime.h>
#include <stdint.h>

// ---- types ----
typedef _Float16 f16x8 __attribute__((ext_vector_type(8)));
typedef _Float16 f16x4 __attribute__((ext_vector_type(4)));
typedef __fp16 h16x2 __attribute__((ext_vector_type(2)));  // cvt_pkrtz return type
typedef float f32x4 __attribute__((ext_vector_type(4)));
typedef float f32x16 __attribute__((ext_vector_type(16)));

#define SEQ 2048
#define NHEADS 8

// async global->LDS, 16B per lane, LDS dest = wave-uniform base + lane*16
#define GLOAD_LDS16(gp, lp)                                                        \
  __builtin_amdgcn_global_load_lds(                                                \
      (const __attribute__((address_space(1))) void*)(uintptr_t)(const void*)(gp), \
      (__attribute__((address_space(3))) void*)(uintptr_t)(void*)(lp), 16, 0, 0)

// barrier that waits LDS ops only (no vmem drain)
__device__ __forceinline__ void barrier_lds() {
  __builtin_amdgcn_s_waitcnt(0xc07f);  // lgkmcnt(0)
  __builtin_amdgcn_s_barrier();
}

__device__ __forceinline__ f16x4 pack4(float a, float b, float c, float d) {
  h16x2 lo = __builtin_amdgcn_cvt_pkrtz(a, b);
  h16x2 hi = __builtin_amdgcn_cvt_pkrtz(c, d);
  f16x4 o;
  o.x = (_Float16)lo.x; o.y = (_Float16)lo.y;
  o.z = (_Float16)hi.x; o.w = (_Float16)hi.y;
  return o;
}

// ---------------- fp32 -> f16 convert (x + 4 weights, one launch) ----------------
__global__ void cvt_all_kernel(const float* __restrict__ x, const float* __restrict__ wq,
                               const float* __restrict__ wk, const float* __restrict__ wv,
                               const float* __restrict__ wo, _Float16* __restrict__ xh,
                               _Float16* __restrict__ wh) {
  int i = blockIdx.x * 256 + threadIdx.x;  // 0 .. 1310719 (f4 units)
  const float* src;
  _Float16* dst;
  int off;
  if (i < 1048576) {
    src = x; dst = xh; off = i;
  } else {
    int j = i - 1048576;
    int sel = j >> 16;
    off = j & 65535;
    src = (sel == 0) ? wq : (sel == 1) ? wk : (sel == 2) ? wv : wo;
    dst = wh + (size_t)sel * 262144;
  }
  float4 v = ((const float4*)src)[off];
  ((f16x4*)dst)[off] = pack4(v.x, v.y, v.z, v.w);
}

// ---------------- shared 128x128 B^T GEMM tile core (f16, double-buffered DMA) ----------------
// lds = 64 KB: buf b at lds + b*16384: As[128][64], Bs[128][64].
// One __syncthreads per kt; next tile's DMA in flight across the whole compute.
__device__ __forceinline__ void gemm_tile_bt(const _Float16* __restrict__ A,
                                             const _Float16* __restrict__ B,
                                             int m0, int n0,
                                             _Float16* lds,
                                             f32x4 (&acc)[4][4]) {
  const int tid = threadIdx.x;
  const int w = tid >> 6, lane = tid & 63;
  const int wr = w >> 1, wc = w & 1;
  const int lrow = lane & 15, q = lane >> 4;
  const int snb = w * 32 + (lane >> 3);
  const int scb = lane & 7;

#pragma unroll
  for (int i = 0; i < 4; ++i)
#pragma unroll
    for (int j = 0; j < 4; ++j)
#pragma unroll
      for (int r = 0; r < 4; ++r) acc[i][j][r] = 0.f;

  // issue kt=0 staging
#pragma unroll
  for (int t = 0; t < 4; ++t) {
    int n = snb + t * 8;
    int cbg = scb ^ (n & 7);
    GLOAD_LDS16(A + (size_t)(m0 + n) * 512 + cbg * 8, lds + (w * 32 + t * 8) * 64);
    GLOAD_LDS16(B + (size_t)(n0 + n) * 512 + cbg * 8, lds + 8192 + (w * 32 + t * 8) * 64);
  }

  for (int kt = 0; kt < 8; ++kt) {  // K=512, BK=64
    __syncthreads();  // kt's DMA landed; prior reads of this buf done
    if (kt < 7) {
      _Float16* nb = lds + ((kt + 1) & 1) * 16384;
#pragma unroll
      for (int t = 0; t < 4; ++t) {
        int n = snb + t * 8;
        int cbg = scb ^ (n & 7);
        GLOAD_LDS16(A + (size_t)(m0 + n) * 512 + (kt + 1) * 64 + cbg * 8, nb + (w * 32 + t * 8) * 64);
        GLOAD_LDS16(B + (size_t)(n0 + n) * 512 + (kt + 1) * 64 + cbg * 8, nb + 8192 + (w * 32 + t * 8) * 64);
      }
    }
    _Float16* As = lds + (kt & 1) * 16384;
    _Float16* Bs = As + 8192;

    f16x8 af[4][2], bfr[4][2];
#pragma unroll
    for (int i = 0; i < 4; ++i) {
      int m = wr * 64 + i * 16 + lrow;
#pragma unroll
      for (int kk = 0; kk < 2; ++kk) {
        int cb = (kk * 4 + q) ^ (m & 7);
        af[i][kk] = *(const f16x8*)(As + m * 64 + cb * 8);
      }
    }
#pragma unroll
    for (int j = 0; j < 4; ++j) {
      int n = wc * 64 + j * 16 + lrow;
#pragma unroll
      for (int kk = 0; kk < 2; ++kk) {
        int cb = (kk * 4 + q) ^ (n & 7);
        bfr[j][kk] = *(const f16x8*)(Bs + n * 64 + cb * 8);
      }
    }
#pragma unroll
    for (int i = 0; i < 4; ++i)
#pragma unroll
      for (int j = 0; j < 4; ++j) {
        acc[i][j] = __builtin_amdgcn_mfma_f32_16x16x32_f16(af[i][0], bfr[j][0], acc[i][j], 0, 0, 0);
        acc[i][j] = __builtin_amdgcn_mfma_f32_16x16x32_f16(af[i][1], bfr[j][1], acc[i][j], 0, 0, 0);
      }
  }
}

// ---------------- QKV projection (768 blocks, coalesced bounce epilogues) ----------------
__global__ __launch_bounds__(256, 2) void qkv_kernel(
    const _Float16* __restrict__ xb, const _Float16* __restrict__ Wq,
    const _Float16* __restrict__ Wk, const _Float16* __restrict__ Wv,
    _Float16* __restrict__ Qo, _Float16* __restrict__ Ko, _Float16* __restrict__ Vto) {
  __shared__ _Float16 pool[32768];  // 64 KB dbuf staging; bounce [128][136] aliases
  const int z = blockIdx.z;
  f32x4 acc[4][4];
  const int tid = threadIdx.x, w = tid >> 6, lane = tid & 63;
  const int wr = w >> 1, wc = w & 1, lcol = lane & 15, q = lane >> 4;

  if (z < 2) {
    const int m0 = blockIdx.y * 128;  // out-feature tile
    const int n0 = blockIdx.x * 128;  // s tile
    gemm_tile_bt((z == 0) ? Wq : Wk, xb, m0, n0, pool, acc);
    _Float16* outp = (z == 0) ? Qo : Ko;
    __syncthreads();  // all reads done; reuse pool as bounce [s 128][c 136]
#pragma unroll
    for (int i = 0; i < 4; ++i) {
      int cl = wr * 64 + i * 16 + q * 4;
#pragma unroll
      for (int j = 0; j < 4; ++j) {
        int s = wc * 64 + j * 16 + lcol;
        *(f16x4*)(pool + s * 136 + cl) =
            pack4(acc[i][j][0], acc[i][j][1], acc[i][j][2], acc[i][j][3]);
      }
    }
    __syncthreads();
#pragma unroll
    for (int it = 0; it < 16; ++it) {
      int srow = it * 8 + (tid >> 5);
      int ch = tid & 31;
      f16x4 v = *(const f16x4*)(pool + srow * 136 + ch * 4);
      *(f16x4*)(outp + (size_t)(n0 + srow) * 512 + m0 + ch * 4) = v;
    }
  } else {
    const int m0 = blockIdx.x * 128;  // s tile
    const int n0 = blockIdx.y * 128;  // feature tile
    gemm_tile_bt(xb, Wv, m0, n0, pool, acc);
    const int bb = m0 >> 11, sl0 = m0 & 2047;
    __syncthreads();  // bounce [c 128][s 136]
#pragma unroll
    for (int i = 0; i < 4; ++i) {
      int s0 = wr * 64 + i * 16 + q * 4;
#pragma unroll
      for (int j = 0; j < 4; ++j) {
        int c = wc * 64 + j * 16 + lcol;
        *(f16x4*)(pool + c * 136 + s0) =
            pack4(acc[i][j][0], acc[i][j][1], acc[i][j][2], acc[i][j][3]);
      }
    }
    __syncthreads();
#pragma unroll
    for (int it = 0; it < 16; ++it) {
      int crow = it * 8 + (tid >> 5);
      int ch = tid & 31;
      int cg = n0 + crow, h = cg >> 6, d = cg & 63;
      f16x4 v = *(const f16x4*)(pool + crow * 136 + ch * 4);
      *(f16x4*)(Vto + ((size_t)((bb * NHEADS + h) * 64 + d)) * SEQ + sl0 + ch * 4) = v;
    }
  }
}

// ---------------- attention helpers: window fragment load + compute ----------------
// LDS tiles are [rows][64] with chunk swizzle f(row) = (row&7) ^ (((row>>3)&1)<<2):
// every aligned 8-lane group hits 8 distinct 16B chunks -> conflict-free b128 reads.
__device__ __forceinline__ void load_win(const _Float16* Ksc, const _Float16* Vtsc,
                                         int m, int klp, int fk, int fq,
                                         int hi, int q31,
                                         f16x8 (&ka)[4], f16x8 (&vb)[2][2]) {
  const int krow = m * 32 + klp;
#pragma unroll
  for (int s = 0; s < 4; ++s) {
    int cb = (s * 2 + hi) ^ fk;
    ka[s] = *(const f16x8*)(Ksc + krow * 64 + cb * 8);
  }
#pragma unroll
  for (int ww = 0; ww < 2; ++ww)
#pragma unroll
    for (int t = 0; t < 2; ++t) {
      int drow = t * 32 + q31;
      int g = m * 4 + ww * 2 + hi;
      int cb = g ^ fq;
      vb[ww][t] = *(const f16x8*)(Vtsc + drow * 64 + cb * 8);
    }
}

__device__ __forceinline__ void attn_window(const f16x8 (&ka)[4], const f16x8 (&vb)[2][2],
                                            const f16x8 (&qb)[4], const f32x16& z16,
                                            f32x16& o0, f32x16& o1) {
  const float c1 = 0.18033688011112042f;  // (1/8)*log2(e); exp2 bias -1 = -11+10 (P x1024)
  __builtin_amdgcn_s_setprio(1);
  f32x16 sacc = __builtin_amdgcn_mfma_f32_32x32x16_f16(ka[0], qb[0], z16, 0, 0, 0);
  sacc = __builtin_amdgcn_mfma_f32_32x32x16_f16(ka[1], qb[1], sacc, 0, 0, 0);
  sacc = __builtin_amdgcn_mfma_f32_32x32x16_f16(ka[2], qb[2], sacc, 0, 0, 0);
  sacc = __builtin_amdgcn_mfma_f32_32x32x16_f16(ka[3], qb[3], sacc, 0, 0, 0);
  __builtin_amdgcn_s_setprio(0);

  float p[16];
#pragma unroll
  for (int r = 0; r < 16; ++r) {
    float wp = __builtin_amdgcn_exp2f(__builtin_fmaf(sacc[r], c1, -1.0f));
    float e = wp * 0.0009765625f;
    p[r] = __builtin_fmaf(wp, __builtin_fmaf(e, e, -e), wp);  // wp*(1-e+e^2)
  }

  f16x8 pa[2];
#pragma unroll
  for (int ww = 0; ww < 2; ++ww) {
    h16x2 a0 = __builtin_amdgcn_cvt_pkrtz(p[8 * ww + 0], p[8 * ww + 1]);
    h16x2 a1 = __builtin_amdgcn_cvt_pkrtz(p[8 * ww + 2], p[8 * ww + 3]);
    h16x2 a2 = __builtin_amdgcn_cvt_pkrtz(p[8 * ww + 4], p[8 * ww + 5]);
    h16x2 a3 = __builtin_amdgcn_cvt_pkrtz(p[8 * ww + 6], p[8 * ww + 7]);
    pa[ww][0] = (_Float16)a0.x; pa[ww][1] = (_Float16)a0.y;
    pa[ww][2] = (_Float16)a1.x; pa[ww][3] = (_Float16)a1.y;
    pa[ww][4] = (_Float16)a2.x; pa[ww][5] = (_Float16)a2.y;
    pa[ww][6] = (_Float16)a3.x; pa[ww][7] = (_Float16)a3.y;
  }

  __builtin_amdgcn_s_setprio(1);
  o0 = __builtin_amdgcn_mfma_f32_32x32x16_f16(pa[0], vb[0][0], o0, 0, 0, 0);
  o1 = __builtin_amdgcn_mfma_f32_32x32x16_f16(pa[0], vb[0][1], o1, 0, 0, 0);
  o0 = __builtin_amdgcn_mfma_f32_32x32x16_f16(pa[1], vb[1][0], o0, 0, 0, 0);
  o1 = __builtin_amdgcn_mfma_f32_32x32x16_f16(pa[1], vb[1][1], o1, 0, 0, 0);
  __builtin_amdgcn_s_setprio(0);
}

// ---------------- sigmoid attention: k-split x2 for occupancy ----------------
// Grid 1024 = (8 xcd) x (4 bh) x (16 qt) x (2 ks). Each block: 128 q-rows x 1024 k.
// KVBLK=64 -> LDS 32 KB (dbuf of K[64][64] + V[64][64]) -> 4 blocks/CU, 4 waves/SIMD
// (2x the old latency hiding). Sigmoid attention has no softmax norm, so the two
// k-half partial outputs simply ADD (combine kernel). Conflict-free chunk swizzle
// f(row) = (row&7) ^ (((row>>3)&1)<<2) on Q/K/V staging+reads.
__global__ __launch_bounds__(256, 4) void attn_kernel(
    const _Float16* __restrict__ Qw, const _Float16* __restrict__ Kw,
    const _Float16* __restrict__ Vtw, _Float16* __restrict__ Ow,
    _Float16* __restrict__ Op) {
  __shared__ _Float16 lds[16384];  // 32 KB: buf b at lds+b*8192: K[64][64], V[64][64]

  const int tid = threadIdx.x, w = tid >> 6, lane = tid & 63;
  const int q31 = lane & 31, hi = lane >> 5;

  // XCD swizzle: 4 bh x 16 qt x 2 ks per XCD (K/V halves stay L2-resident)
  const int L = blockIdx.x;
  const int xcd = L & 7, slot = L >> 3;
  const int bh = xcd * 4 + (slot >> 5);
  const int rem = slot & 31;
  const int qt = rem >> 1, ks = rem & 1;
  const int b = bh >> 3, h = bh & 7;
  const int q0 = qt * 128;

  const _Float16* Qp = Qw + ((size_t)(b * SEQ + q0)) * 512 + h * 64;
  const _Float16* Kp = Kw + ((size_t)b * SEQ) * 512 + h * 64 + (size_t)ks * 1024 * 512;
  const _Float16* Vp = Vtw + (size_t)bh * 64 * SEQ + (size_t)ks * 1024;

  const int l3 = lane >> 3, l7 = lane & 7;

  // per-lane byte offsets (kt-invariant)
  int koff[2], voff[2];
#pragma unroll
  for (int t = 0; t < 2; ++t) {
    int n = w * 16 + t * 8 + l3;
    int cbg = l7 ^ l3 ^ ((t & 1) << 2);
    koff[t] = n * 1024 + cbg * 16;  // K source: row n (s-index), 16B chunk
    voff[t] = n * 4096 + cbg * 16;  // V source: row n (d-index), stride SEQ*2B
  }
  const char* kgb = (const char*)Kp;
  const char* vgb = (const char*)Vp;

  // prologue: Q tile [128][64] -> buf1 (8 KB x2? Q=16KB spans buf1's 8192 halves);
  // K0/V0 -> buf0. All DMA overlapped, one sync.
  _Float16* Qs = lds + 8192;  // 16 KB Q tile == entire buf1
#pragma unroll
  for (int t = 0; t < 4; ++t) {
    int n = w * 32 + t * 8 + l3;
    int cbg = l7 ^ l3 ^ ((t & 1) << 2);
    GLOAD_LDS16((const char*)Qp + n * 1024 + cbg * 16, Qs + (w * 32 + t * 8) * 64);
  }
#pragma unroll
  for (int t = 0; t < 2; ++t) {
    GLOAD_LDS16(kgb + koff[t], lds + (w * 16 + t * 8) * 64);
    GLOAD_LDS16(vgb + voff[t], lds + 4096 + (w * 16 + t * 8) * 64);
  }
  kgb += 65536;  // next 64 k-rows
  vgb += 128;    // next 64 k-cols (2B each)
  __syncthreads();

  const int fq = (q31 & 7) ^ (((q31 >> 3) & 1) << 2);
  // K A-frag lane->row permutation: swap bits 2,3 of (lane&31)
  const int klp = (q31 & 3) | ((q31 & 4) << 1) | ((q31 & 8) >> 1) | (q31 & 16);
  const int fk = (klp & 7) ^ (((klp >> 3) & 1) << 2);

  // wave's own 32 q-rows: Q B-frags per d-slice s (lane: col=q31, d=s*16+hi*8+j)
  f16x8 qb[4];
  const int qrow = w * 32 + q31;
#pragma unroll
  for (int s = 0; s < 4; ++s) {
    int cb = (s * 2 + hi) ^ fq;
    qb[s] = *(const f16x8*)(Qs + qrow * 64 + cb * 8);
  }
  // NOTE: no barrier here. Loop-top __syncthreads drains qb ds_reads (lgkmcnt) in every
  // wave before any wave can issue the kt=1 DMA that overwrites the Q region (buf1).

  f32x16 oacc[2];
  f32x16 z16;
#pragma unroll
  for (int r = 0; r < 16; ++r) { z16[r] = 0.f; oacc[0][r] = 0.f; oacc[1][r] = 0.f; }

  for (int kt = 0; kt < 16; ++kt) {  // 1024 k / 64
    __syncthreads();  // kt's DMA landed (issued one iter ago); prev buf reads done
    if (kt < 15) {
      _Float16* nb = lds + ((kt + 1) & 1) * 8192;
#pragma unroll
      for (int t = 0; t < 2; ++t) {
        GLOAD_LDS16(kgb + koff[t], nb + (w * 16 + t * 8) * 64);
        GLOAD_LDS16(vgb + voff[t], nb + 4096 + (w * 16 + t * 8) * 64);
      }
      kgb += 65536;
      vgb += 128;
    }
    const _Float16* Ksc = lds + (kt & 1) * 8192;
    const _Float16* Vtsc = Ksc + 4096;

    // 2 windows of 32 k each
    f16x8 ka0[4], ka1[4], vb0[2][2], vb1[2][2];
    load_win(Ksc, Vtsc, 0, klp, fk, fq, hi, q31, ka0, vb0);
    attn_window(ka0, vb0, qb, z16, oacc[0], oacc[1]);
    load_win(Ksc, Vtsc, 1, klp, fk, fq, hi, q31, ka1, vb1);
    attn_window(ka1, vb1, qb, z16, oacc[0], oacc[1]);
  }

  // epilogue: descale, bounce through LDS, coalesced 128B row stores (partial output)
  barrier_lds();       // all waves' LDS reads done; no DMA outstanding (kt=15 skipped)
  _Float16* Ob = lds;  // [128][72] = 18 KB <= 32 KB
  _Float16* outp = ks ? Op : Ow;
#pragma unroll
  for (int t = 0; t < 2; ++t) {
#pragma unroll
    for (int r = 0; r < 16; ++r) {
      int row = w * 32 + (r & 3) + ((r >> 2) << 3) + hi * 4;
      int d = t * 32 + q31;
      Ob[row * 72 + d] = (_Float16)(oacc[t][r] * 0.0009765625f);
    }
  }
  barrier_lds();
#pragma unroll
  for (int it = 0; it < 8; ++it) {
    int row = it * 16 + (tid >> 4);
    int ch = tid & 15;
    f16x4 v = *(const f16x4*)(Ob + row * 72 + ch * 4);
    *(f16x4*)(outp + (size_t)(b * SEQ + q0 + row) * 512 + h * 64 + ch * 4) = v;
  }
}

// ---------------- combine: Ow += Op (k-split partial sum) ----------------
__global__ void combine_kernel(_Float16* __restrict__ o, const _Float16* __restrict__ p) {
  int i = blockIdx.x * 256 + threadIdx.x;  // 524288 f16x8 units (4 B*S*D halves / 8)
  f16x8 a = ((const f16x8*)o)[i];
  f16x8 c = ((const f16x8*)p)[i];
  ((f16x8*)o)[i] = a + c;
}

// ---------------- output projection (fp32 out, coalesced) ----------------
__global__ __launch_bounds__(256, 2) void oproj_kernel(
    const _Float16* __restrict__ A, const _Float16* __restrict__ Wo,
    float* __restrict__ out) {
  __shared__ _Float16 pool[32768];  // 64 KB dbuf
  const int m0 = blockIdx.x * 128, n0 = blockIdx.y * 128;
  f32x4 acc[4][4];
  gemm_tile_bt(A, Wo, m0, n0, pool, acc);

  const int tid = threadIdx.x, w = tid >> 6, lane = tid & 63;
  const int wr = w >> 1, wc = w & 1, lcol = lane & 15, q = lane >> 4;
#pragma unroll
  for (int i = 0; i < 4; ++i) {
    int gm0 = m0 + wr * 64 + i * 16 + q * 4;
#pragma unroll
    for (int j = 0; j < 4; ++j) {
      int gn = n0 + wc * 64 + j * 16 + lcol;
#pragma unroll
      for (int r = 0; r < 4; ++r)
        out[(size_t)(gm0 + r) * 512 + gn] = acc[i][j][r];
    }
  }
}

// ---------------- launch ----------------
extern "C" void kernel_launch(void* const* d_in, const int* in_sizes, int n_in,
                              void* d_out, int out_size, void* d_ws, size_t ws_size,
                              hipStream_t stream) {
  const float* x = (const float*)d_in[0];
  const float* Wq = (const float*)d_in[1];
  const float* Wk = (const float*)d_in[2];
  const float* Wv = (const float*)d_in[3];
  const float* Wo = (const float*)d_in[4];
  float* out = (float*)d_out;
  char* ws = (char*)d_ws;

  _Float16* xh = (_Float16*)(ws + 0);          // 8 MB [8192][512]; dead after qkv -> reused as Op
  _Float16* wh = (_Float16*)(ws + 8388608);    // 4 x 512 KB (q,k,v,o)
  _Float16* Qw = (_Float16*)(ws + 10485760);   // 8 MB [8192][512]
  _Float16* Kw = (_Float16*)(ws + 18874368);   // 8 MB [8192][512]
  _Float16* Vtw = (_Float16*)(ws + 27262976);  // 8 MB [B,H,D,S]
  _Float16* Ow = (_Float16*)(ws + 35651584);   // 8 MB [8192][512]

  _Float16* wqh = wh;
  _Float16* wkh = wh + 262144;
  _Float16* wvh = wh + 524288;
  _Float16* woh = wh + 786432;

  cvt_all_kernel<<<5120, 256, 0, stream>>>(x, Wq, Wk, Wv, Wo, xh, wh);
  qkv_kernel<<<dim3(64, 4, 3), 256, 0, stream>>>(xh, wqh, wkh, wvh, Qw, Kw, Vtw);
  attn_kernel<<<1024, 256, 0, stream>>>(Qw, Kw, Vtw, Ow, xh);  // xh reused as ks=1 partial
  combine_kernel<<<2048, 256, 0, stream>>>(Ow, xh);
  oproj_kernel<<<dim3(64, 4), 256, 0, stream>>>(Ow, woh, out);
}

// Round 4
// 149.782 us; speedup vs baseline: 1.0807x; 1.0807x over previous
//
#include <hip/hip_runtime.h>
#include <stdint.h>

// ---- types ----
typedef _Float16 f16x8 __attribute__((ext_vector_type(8)));
typedef _Float16 f16x4 __attribute__((ext_vector_type(4)));
typedef __fp16 h16x2 __attribute__((ext_vector_type(2)));  // cvt_pkrtz return type
typedef float f32x4 __attribute__((ext_vector_type(4)));
typedef float f32x16 __attribute__((ext_vector_type(16)));

#define SEQ 2048
#define NHEADS 8

// async global->LDS, 16B per lane, LDS dest = wave-uniform base + lane*16
#define GLOAD_LDS16(gp, lp)                                                        \
  __builtin_amdgcn_global_load_lds(                                                \
      (const __attribute__((address_space(1))) void*)(uintptr_t)(const void*)(gp), \
      (__attribute__((address_space(3))) void*)(uintptr_t)(void*)(lp), 16, 0, 0)

// pinned LDS read: compiler cannot sink/re-roll these (volatile asm keeps program order)
#define DSR(dst, base, off) \
  asm volatile("ds_read_b128 %0, %1 offset:%c2" : "=v"(dst) : "v"(base), "i"(off))

// counted LDS-op wait + scheduler fence (rule: sched_barrier needed so MFMA can't hoist above)
#define WAIT_LGKM(n)                                         \
  do {                                                       \
    asm volatile("s_waitcnt lgkmcnt(%c0)" ::"i"(n) : "memory"); \
    __builtin_amdgcn_sched_barrier(0);                       \
  } while (0)

// barrier that waits LDS ops only (no vmem drain)
__device__ __forceinline__ void barrier_lds() {
  __builtin_amdgcn_s_waitcnt(0xc07f);  // lgkmcnt(0)
  __builtin_amdgcn_s_barrier();
}

__device__ __forceinline__ f16x4 pack4(float a, float b, float c, float d) {
  h16x2 lo = __builtin_amdgcn_cvt_pkrtz(a, b);
  h16x2 hi = __builtin_amdgcn_cvt_pkrtz(c, d);
  f16x4 o;
  o.x = (_Float16)lo.x; o.y = (_Float16)lo.y;
  o.z = (_Float16)hi.x; o.w = (_Float16)hi.y;
  return o;
}

// ---------------- fp32 -> f16 convert (x + 4 weights, one launch) ----------------
__global__ void cvt_all_kernel(const float* __restrict__ x, const float* __restrict__ wq,
                               const float* __restrict__ wk, const float* __restrict__ wv,
                               const float* __restrict__ wo, _Float16* __restrict__ xh,
                               _Float16* __restrict__ wh) {
  int i = blockIdx.x * 256 + threadIdx.x;  // 0 .. 1310719 (f4 units)
  const float* src;
  _Float16* dst;
  int off;
  if (i < 1048576) {
    src = x; dst = xh; off = i;
  } else {
    int j = i - 1048576;
    int sel = j >> 16;
    off = j & 65535;
    src = (sel == 0) ? wq : (sel == 1) ? wk : (sel == 2) ? wv : wo;
    dst = wh + (size_t)sel * 262144;
  }
  float4 v = ((const float4*)src)[off];
  ((f16x4*)dst)[off] = pack4(v.x, v.y, v.z, v.w);
}

// ---------------- shared 128x128 B^T GEMM tile core (f16, double-buffered DMA) ----------------
__device__ __forceinline__ void gemm_tile_bt(const _Float16* __restrict__ A,
                                             const _Float16* __restrict__ B,
                                             int m0, int n0,
                                             _Float16* lds,
                                             f32x4 (&acc)[4][4]) {
  const int tid = threadIdx.x;
  const int w = tid >> 6, lane = tid & 63;
  const int wr = w >> 1, wc = w & 1;
  const int lrow = lane & 15, q = lane >> 4;
  const int snb = w * 32 + (lane >> 3);
  const int scb = lane & 7;

#pragma unroll
  for (int i = 0; i < 4; ++i)
#pragma unroll
    for (int j = 0; j < 4; ++j)
#pragma unroll
      for (int r = 0; r < 4; ++r) acc[i][j][r] = 0.f;

#pragma unroll
  for (int t = 0; t < 4; ++t) {
    int n = snb + t * 8;
    int cbg = scb ^ (n & 7);
    GLOAD_LDS16(A + (size_t)(m0 + n) * 512 + cbg * 8, lds + (w * 32 + t * 8) * 64);
    GLOAD_LDS16(B + (size_t)(n0 + n) * 512 + cbg * 8, lds + 8192 + (w * 32 + t * 8) * 64);
  }

  for (int kt = 0; kt < 8; ++kt) {  // K=512, BK=64
    __syncthreads();
    if (kt < 7) {
      _Float16* nb = lds + ((kt + 1) & 1) * 16384;
#pragma unroll
      for (int t = 0; t < 4; ++t) {
        int n = snb + t * 8;
        int cbg = scb ^ (n & 7);
        GLOAD_LDS16(A + (size_t)(m0 + n) * 512 + (kt + 1) * 64 + cbg * 8, nb + (w * 32 + t * 8) * 64);
        GLOAD_LDS16(B + (size_t)(n0 + n) * 512 + (kt + 1) * 64 + cbg * 8, nb + 8192 + (w * 32 + t * 8) * 64);
      }
    }
    _Float16* As = lds + (kt & 1) * 16384;
    _Float16* Bs = As + 8192;

    f16x8 af[4][2], bfr[4][2];
#pragma unroll
    for (int i = 0; i < 4; ++i) {
      int m = wr * 64 + i * 16 + lrow;
#pragma unroll
      for (int kk = 0; kk < 2; ++kk) {
        int cb = (kk * 4 + q) ^ (m & 7);
        af[i][kk] = *(const f16x8*)(As + m * 64 + cb * 8);
      }
    }
#pragma unroll
    for (int j = 0; j < 4; ++j) {
      int n = wc * 64 + j * 16 + lrow;
#pragma unroll
      for (int kk = 0; kk < 2; ++kk) {
        int cb = (kk * 4 + q) ^ (n & 7);
        bfr[j][kk] = *(const f16x8*)(Bs + n * 64 + cb * 8);
      }
    }
#pragma unroll
    for (int i = 0; i < 4; ++i)
#pragma unroll
      for (int j = 0; j < 4; ++j) {
        acc[i][j] = __builtin_amdgcn_mfma_f32_16x16x32_f16(af[i][0], bfr[j][0], acc[i][j], 0, 0, 0);
        acc[i][j] = __builtin_amdgcn_mfma_f32_16x16x32_f16(af[i][1], bfr[j][1], acc[i][j], 0, 0, 0);
      }
  }
}

// ---------------- QKV projection ----------------
__global__ __launch_bounds__(256, 2) void qkv_kernel(
    const _Float16* __restrict__ xb, const _Float16* __restrict__ Wq,
    const _Float16* __restrict__ Wk, const _Float16* __restrict__ Wv,
    _Float16* __restrict__ Qo, _Float16* __restrict__ Ko, _Float16* __restrict__ Vto) {
  __shared__ _Float16 pool[32768];  // 64 KB dbuf staging; bounce [128][136] aliases
  const int z = blockIdx.z;
  f32x4 acc[4][4];
  const int tid = threadIdx.x, w = tid >> 6, lane = tid & 63;
  const int wr = w >> 1, wc = w & 1, lcol = lane & 15, q = lane >> 4;

  if (z < 2) {
    const int m0 = blockIdx.y * 128;  // out-feature tile
    const int n0 = blockIdx.x * 128;  // s tile
    gemm_tile_bt((z == 0) ? Wq : Wk, xb, m0, n0, pool, acc);
    _Float16* outp = (z == 0) ? Qo : Ko;
    __syncthreads();
#pragma unroll
    for (int i = 0; i < 4; ++i) {
      int cl = wr * 64 + i * 16 + q * 4;
#pragma unroll
      for (int j = 0; j < 4; ++j) {
        int s = wc * 64 + j * 16 + lcol;
        *(f16x4*)(pool + s * 136 + cl) =
            pack4(acc[i][j][0], acc[i][j][1], acc[i][j][2], acc[i][j][3]);
      }
    }
    __syncthreads();
#pragma unroll
    for (int it = 0; it < 16; ++it) {
      int srow = it * 8 + (tid >> 5);
      int ch = tid & 31;
      f16x4 v = *(const f16x4*)(pool + srow * 136 + ch * 4);
      *(f16x4*)(outp + (size_t)(n0 + srow) * 512 + m0 + ch * 4) = v;
    }
  } else {
    const int m0 = blockIdx.x * 128;  // s tile
    const int n0 = blockIdx.y * 128;  // feature tile
    gemm_tile_bt(xb, Wv, m0, n0, pool, acc);
    const int bb = m0 >> 11, sl0 = m0 & 2047;
    __syncthreads();
#pragma unroll
    for (int i = 0; i < 4; ++i) {
      int s0 = wr * 64 + i * 16 + q * 4;
#pragma unroll
      for (int j = 0; j < 4; ++j) {
        int c = wc * 64 + j * 16 + lcol;
        *(f16x4*)(pool + c * 136 + s0) =
            pack4(acc[i][j][0], acc[i][j][1], acc[i][j][2], acc[i][j][3]);
      }
    }
    __syncthreads();
#pragma unroll
    for (int it = 0; it < 16; ++it) {
      int crow = it * 8 + (tid >> 5);
      int ch = tid & 31;
      int cg = n0 + crow, h = cg >> 6, d = cg & 63;
      f16x4 v = *(const f16x4*)(pool + crow * 136 + ch * 4);
      *(f16x4*)(Vto + ((size_t)((bb * NHEADS + h) * 64 + d)) * SEQ + sl0 + ch * 4) = v;
    }
  }
}

// ---------------- attention window compute (regs in -> oacc) ----------------
__device__ __forceinline__ void attn_window(
    f16x8 k0, f16x8 k1, f16x8 k2, f16x8 k3,
    f16x8 v00, f16x8 v01, f16x8 v10, f16x8 v11,
    const f16x8 (&qb)[4], const f32x16& z16, f32x16& o0, f32x16& o1) {
  const float c1 = 0.18033688011112042f;  // (1/8)*log2(e); exp2 bias -1 = -11+10 (P x1024)
  __builtin_amdgcn_s_setprio(1);
  f32x16 s = __builtin_amdgcn_mfma_f32_32x32x16_f16(k0, qb[0], z16, 0, 0, 0);
  s = __builtin_amdgcn_mfma_f32_32x32x16_f16(k1, qb[1], s, 0, 0, 0);
  s = __builtin_amdgcn_mfma_f32_32x32x16_f16(k2, qb[2], s, 0, 0, 0);
  s = __builtin_amdgcn_mfma_f32_32x32x16_f16(k3, qb[3], s, 0, 0, 0);
  __builtin_amdgcn_s_setprio(0);

  float p[16];
#pragma unroll
  for (int r = 0; r < 16; ++r) {
    float wp = __builtin_amdgcn_exp2f(__builtin_fmaf(s[r], c1, -1.0f));
    float e = wp * 0.0009765625f;
    p[r] = __builtin_fmaf(wp, __builtin_fmaf(e, e, -e), wp);  // wp*(1-e+e^2)
  }

  f16x8 pa0, pa1;
  {
    h16x2 a0 = __builtin_amdgcn_cvt_pkrtz(p[0], p[1]);
    h16x2 a1 = __builtin_amdgcn_cvt_pkrtz(p[2], p[3]);
    h16x2 a2 = __builtin_amdgcn_cvt_pkrtz(p[4], p[5]);
    h16x2 a3 = __builtin_amdgcn_cvt_pkrtz(p[6], p[7]);
    pa0[0] = (_Float16)a0.x; pa0[1] = (_Float16)a0.y;
    pa0[2] = (_Float16)a1.x; pa0[3] = (_Float16)a1.y;
    pa0[4] = (_Float16)a2.x; pa0[5] = (_Float16)a2.y;
    pa0[6] = (_Float16)a3.x; pa0[7] = (_Float16)a3.y;
    h16x2 b0 = __builtin_amdgcn_cvt_pkrtz(p[8], p[9]);
    h16x2 b1 = __builtin_amdgcn_cvt_pkrtz(p[10], p[11]);
    h16x2 b2 = __builtin_amdgcn_cvt_pkrtz(p[12], p[13]);
    h16x2 b3 = __builtin_amdgcn_cvt_pkrtz(p[14], p[15]);
    pa1[0] = (_Float16)b0.x; pa1[1] = (_Float16)b0.y;
    pa1[2] = (_Float16)b1.x; pa1[3] = (_Float16)b1.y;
    pa1[4] = (_Float16)b2.x; pa1[5] = (_Float16)b2.y;
    pa1[6] = (_Float16)b3.x; pa1[7] = (_Float16)b3.y;
  }

  __builtin_amdgcn_s_setprio(1);
  o0 = __builtin_amdgcn_mfma_f32_32x32x16_f16(pa0, v00, o0, 0, 0, 0);
  o1 = __builtin_amdgcn_mfma_f32_32x32x16_f16(pa0, v01, o1, 0, 0, 0);
  o0 = __builtin_amdgcn_mfma_f32_32x32x16_f16(pa1, v10, o0, 0, 0, 0);
  o1 = __builtin_amdgcn_mfma_f32_32x32x16_f16(pa1, v11, o1, 0, 0, 0);
  __builtin_amdgcn_s_setprio(0);
}

// one kt step: barrier, prefetch kt+1 DMA, issue ALL 16 frag reads (pinned asm),
// counted-wait(8) -> window A (B's reads in flight), wait(0) -> window B.
#define KT_BODY(BUFB, NBUFB, PF)                                              \
  {                                                                           \
    __syncthreads();                                                          \
    if (PF) {                                                                 \
      _Float16* nb = (_Float16*)((char*)lds + (NBUFB));                       \
      GLOAD_LDS16(kgb + koff[0], nb + (w * 16) * 64);                         \
      GLOAD_LDS16(kgb + koff[1], nb + (w * 16 + 8) * 64);                     \
      GLOAD_LDS16(vgb + voff[0], nb + 4096 + (w * 16) * 64);                  \
      GLOAD_LDS16(vgb + voff[1], nb + 4096 + (w * 16 + 8) * 64);              \
      kgb += 65536;                                                           \
      vgb += 128;                                                             \
    }                                                                         \
    f16x8 kA0, kA1, kA2, kA3, vA00, vA01, vA10, vA11;                         \
    f16x8 kB0, kB1, kB2, kB3, vB00, vB01, vB10, vB11;                         \
    DSR(kA0, kb0, (BUFB));                                                    \
    DSR(kA1, kb1, (BUFB));                                                    \
    DSR(kA2, kb2, (BUFB));                                                    \
    DSR(kA3, kb3, (BUFB));                                                    \
    DSR(vA00, pv00, (BUFB) + 8192);                                           \
    DSR(vA01, pv00, (BUFB) + 12288);                                          \
    DSR(vA10, pv01, (BUFB) + 8192);                                           \
    DSR(vA11, pv01, (BUFB) + 12288);                                          \
    DSR(kB0, kb0, (BUFB) + 4096);                                             \
    DSR(kB1, kb1, (BUFB) + 4096);                                             \
    DSR(kB2, kb2, (BUFB) + 4096);                                             \
    DSR(kB3, kb3, (BUFB) + 4096);                                             \
    DSR(vB00, pv10, (BUFB) + 8192);                                           \
    DSR(vB01, pv10, (BUFB) + 12288);                                          \
    DSR(vB10, pv11, (BUFB) + 8192);                                           \
    DSR(vB11, pv11, (BUFB) + 12288);                                          \
    WAIT_LGKM(8);                                                             \
    attn_window(kA0, kA1, kA2, kA3, vA00, vA01, vA10, vA11, qb, z16, oacc0, oacc1); \
    WAIT_LGKM(0);                                                             \
    attn_window(kB0, kB1, kB2, kB3, vB00, vB01, vB10, vB11, qb, z16, oacc0, oacc1); \
  }

// ---------------- sigmoid attention: pinned-asm 2-window pipeline ----------------
// Grid 512 = (8 xcd) x (4 bh) x (16 qt). Block: 128 q-rows x full 2048 k, KVBLK=64,
// LDS 32 KB dbuf (K[64][64] + V[64][64] per buf). Swapped QK^T (S^T = K.Q^T) with
// bit2<->3-swapped K rows feeds PV A-frags straight from C-regs. All fragment reads
// are volatile-asm ds_read_b128 with literal offsets + counted lgkmcnt waits: the
// compiler cannot re-roll the pipeline (r2/r3 failure mode, VGPR 60 proved JIT loads).
__global__ __launch_bounds__(256, 2) void attn_kernel(
    const _Float16* __restrict__ Qw, const _Float16* __restrict__ Kw,
    const _Float16* __restrict__ Vtw, _Float16* __restrict__ Ow) {
  __shared__ _Float16 lds[16384];  // 32 KB: buf b at byte b*16384: K[64][64], V[64][64]

  const int tid = threadIdx.x, w = tid >> 6, lane = tid & 63;
  const int q31 = lane & 31, hi = lane >> 5;

  // XCD swizzle: 4 bh x 16 q-tiles per XCD (K/V stay L2-resident)
  const int L = blockIdx.x;
  const int xcd = L & 7, slot = L >> 3;
  const int bh = xcd * 4 + (slot >> 4), qt = slot & 15;
  const int b = bh >> 3, h = bh & 7;
  const int q0 = qt * 128;

  const _Float16* Qp = Qw + ((size_t)(b * SEQ + q0)) * 512 + h * 64;
  const _Float16* Kp = Kw + ((size_t)b * SEQ) * 512 + h * 64;
  const _Float16* Vp = Vtw + (size_t)bh * 64 * SEQ;

  const int l3 = lane >> 3, l7 = lane & 7;

  // per-lane DMA byte offsets (kt-invariant)
  int koff[2], voff[2];
#pragma unroll
  for (int t = 0; t < 2; ++t) {
    int n = w * 16 + t * 8 + l3;
    int cbg = l7 ^ l3 ^ ((t & 1) << 2);
    koff[t] = n * 1024 + cbg * 16;  // K source: row n (s-index)
    voff[t] = n * 4096 + cbg * 16;  // V source: row n (d-index), stride SEQ*2B
  }
  const char* kgb = (const char*)Kp;
  const char* vgb = (const char*)Vp;

  // prologue: Q tile [128][64] -> buf1 (bytes 16384..); K0/V0 -> buf0. One sync.
  _Float16* Qs = lds + 8192;  // halves; byte 16384
#pragma unroll
  for (int t = 0; t < 4; ++t) {
    int n = w * 32 + t * 8 + l3;
    int cbg = l7 ^ l3 ^ ((t & 1) << 2);
    GLOAD_LDS16((const char*)Qp + n * 1024 + cbg * 16, Qs + (w * 32 + t * 8) * 64);
  }
  GLOAD_LDS16(kgb + koff[0], lds + (w * 16) * 64);
  GLOAD_LDS16(kgb + koff[1], lds + (w * 16 + 8) * 64);
  GLOAD_LDS16(vgb + voff[0], lds + 4096 + (w * 16) * 64);
  GLOAD_LDS16(vgb + voff[1], lds + 4096 + (w * 16 + 8) * 64);
  kgb += 65536;
  vgb += 128;
  __syncthreads();

  const int fq = (q31 & 7) ^ (((q31 >> 3) & 1) << 2);
  // K A-frag lane->row permutation: swap bits 2,3 of (lane&31)
  const int klp = (q31 & 3) | ((q31 & 4) << 1) | ((q31 & 8) >> 1) | (q31 & 16);
  const int fk = (klp & 7) ^ (((klp >> 3) & 1) << 2);

  // wave's own 32 q-rows: Q B-frags per d-slice s
  f16x8 qb[4];
  const int qrow = w * 32 + q31;
#pragma unroll
  for (int s = 0; s < 4; ++s) {
    int cb = (s * 2 + hi) ^ fq;
    qb[s] = *(const f16x8*)(Qs + qrow * 64 + cb * 8);
  }
  // (first KT_BODY's __syncthreads drains these reads in all waves before kt1 DMA
  //  overwrites buf1 = the Q region)

  // per-lane LDS byte-address bases for pinned fragment reads
  const int kb0 = klp * 128 + (((0 * 2 + hi) ^ fk) << 4);
  const int kb1 = klp * 128 + (((1 * 2 + hi) ^ fk) << 4);
  const int kb2 = klp * 128 + (((2 * 2 + hi) ^ fk) << 4);
  const int kb3 = klp * 128 + (((3 * 2 + hi) ^ fk) << 4);
  const int pv00 = q31 * 128 + (((0 + 0 + hi) ^ fq) << 4);  // m=0, ww=0
  const int pv01 = q31 * 128 + (((0 + 2 + hi) ^ fq) << 4);  // m=0, ww=1
  const int pv10 = q31 * 128 + (((4 + 0 + hi) ^ fq) << 4);  // m=1, ww=0
  const int pv11 = q31 * 128 + (((4 + 2 + hi) ^ fq) << 4);  // m=1, ww=1

  f32x16 oacc0, oacc1, z16;
#pragma unroll
  for (int r = 0; r < 16; ++r) { z16[r] = 0.f; oacc0[r] = 0.f; oacc1[r] = 0.f; }

  for (int p = 0; p < 16; ++p) {  // 32 kt of 64 k, unrolled x2 for literal buf offsets
    KT_BODY(0, 16384, true);
    KT_BODY(16384, 0, (p < 15));
  }

  // epilogue: descale, bounce through LDS, coalesced 128B row stores
  barrier_lds();       // all waves' reads done; no DMA outstanding (kt31 not prefetched past)
  _Float16* Ob = lds;  // [128][72] = 18 KB
#pragma unroll
  for (int t = 0; t < 2; ++t) {
#pragma unroll
    for (int r = 0; r < 16; ++r) {
      int row = w * 32 + (r & 3) + ((r >> 2) << 3) + hi * 4;
      int d = t * 32 + q31;
      float v = (t == 0) ? oacc0[r] : oacc1[r];
      Ob[row * 72 + d] = (_Float16)(v * 0.0009765625f);
    }
  }
  barrier_lds();
#pragma unroll
  for (int it = 0; it < 8; ++it) {
    int row = it * 16 + (tid >> 4);
    int ch = tid & 15;
    f16x4 v = *(const f16x4*)(Ob + row * 72 + ch * 4);
    *(f16x4*)(Ow + (size_t)(b * SEQ + q0 + row) * 512 + h * 64 + ch * 4) = v;
  }
}

// ---------------- output projection (fp32 out, coalesced) ----------------
__global__ __launch_bounds__(256, 2) void oproj_kernel(
    const _Float16* __restrict__ A, const _Float16* __restrict__ Wo,
    float* __restrict__ out) {
  __shared__ _Float16 pool[32768];  // 64 KB dbuf
  const int m0 = blockIdx.x * 128, n0 = blockIdx.y * 128;
  f32x4 acc[4][4];
  gemm_tile_bt(A, Wo, m0, n0, pool, acc);

  const int tid = threadIdx.x, w = tid >> 6, lane = tid & 63;
  const int wr = w >> 1, wc = w & 1, lcol = lane & 15, q = lane >> 4;
#pragma unroll
  for (int i = 0; i < 4; ++i) {
    int gm0 = m0 + wr * 64 + i * 16 + q * 4;
#pragma unroll
    for (int j = 0; j < 4; ++j) {
      int gn = n0 + wc * 64 + j * 16 + lcol;
#pragma unroll
      for (int r = 0; r < 4; ++r)
        out[(size_t)(gm0 + r) * 512 + gn] = acc[i][j][r];
    }
  }
}

// ---------------- launch ----------------
extern "C" void kernel_launch(void* const* d_in, const int* in_sizes, int n_in,
                              void* d_out, int out_size, void* d_ws, size_t ws_size,
                              hipStream_t stream) {
  const float* x = (const float*)d_in[0];
  const float* Wq = (const float*)d_in[1];
  const float* Wk = (const float*)d_in[2];
  const float* Wv = (const float*)d_in[3];
  const float* Wo = (const float*)d_in[4];
  float* out = (float*)d_out;
  char* ws = (char*)d_ws;

  _Float16* xh = (_Float16*)(ws + 0);          // 8 MB [8192][512]
  _Float16* wh = (_Float16*)(ws + 8388608);    // 4 x 512 KB (q,k,v,o)
  _Float16* Qw = (_Float16*)(ws + 10485760);   // 8 MB [8192][512]
  _Float16* Kw = (_Float16*)(ws + 18874368);   // 8 MB [8192][512]
  _Float16* Vtw = (_Float16*)(ws + 27262976);  // 8 MB [B,H,D,S]
  _Float16* Ow = (_Float16*)(ws + 35651584);   // 8 MB [8192][512]

  _Float16* wqh = wh;
  _Float16* wkh = wh + 262144;
  _Float16* wvh = wh + 524288;
  _Float16* woh = wh + 786432;

  cvt_all_kernel<<<5120, 256, 0, stream>>>(x, Wq, Wk, Wv, Wo, xh, wh);
  qkv_kernel<<<dim3(64, 4, 3), 256, 0, stream>>>(xh, wqh, wkh, wvh, Qw, Kw, Vtw);
  attn_kernel<<<512, 256, 0, stream>>>(Qw, Kw, Vtw, Ow);
  oproj_kernel<<<dim3(64, 4), 256, 0, stream>>>(Ow, woh, out);
}